// Round 7
// baseline (166.096 us; speedup 1.0000x reference)
//
#include <hip/hip_runtime.h>
#include <hip/hip_bf16.h>
#include <stdint.h>

#define B_ 8
#define N_ 1024
#define E_ 768
#define H_ 12
#define HD_ 64
#define M_ (B_ * N_)   // 8192 rows

typedef __attribute__((ext_vector_type(8))) short bf8_t;   // 8 x bf16 (4 VGPR)
typedef __attribute__((ext_vector_type(4))) float f4_t;    // 4 x f32

__device__ __forceinline__ unsigned short f2bf(float f) {
  unsigned u = __builtin_bit_cast(unsigned, f);
  unsigned r = (u + 0x7fffu + ((u >> 16) & 1u)) >> 16;  // RNE
  return (unsigned short)r;
}

__device__ __forceinline__ unsigned cvt_pk_bf16(float lo, float hi) {
  unsigned r;
  asm("v_cvt_pk_bf16_f32 %0, %1, %2" : "=v"(r) : "v"(lo), "v"(hi));
  return r;
}

__device__ __forceinline__ void load_lds16(const void* g, void* l) {
  __builtin_amdgcn_global_load_lds(
      (__attribute__((address_space(1))) void*)(g),
      (__attribute__((address_space(3))) void*)(l), 16, 0, 0);
}

// XOR swizzle on the 8-element (16B) chunk index within a 64-elem (128B) row.
__device__ __forceinline__ int swz(int row) {
  return ((row ^ (row >> 3)) & 7) << 3;
}

#define F3(a, b, c) fmaxf(fmaxf((a), (b)), (c))   // fuses to v_max3_f32

// ---------------- weight fp32 -> bf16 cast (vectorized) ----------------
__global__ void k_cast_bf16(const float* __restrict__ in,
                            unsigned short* __restrict__ out, int n4) {
  int i = blockIdx.x * blockDim.x + threadIdx.x;
  if (i < n4) {
    float4 v = ((const float4*)in)[i];
    ushort4 o;
    o.x = f2bf(v.x); o.y = f2bf(v.y); o.z = f2bf(v.z); o.w = f2bf(v.w);
    ((ushort4*)out)[i] = o;
  }
}

// ---------------- LayerNorm -> bf16 (float4 loads, ushort4 stores) ----------
__global__ __launch_bounds__(192) void k_ln(const float* __restrict__ x,
                                            const float* __restrict__ g,
                                            const float* __restrict__ bta,
                                            unsigned short* __restrict__ xn) {
  int row = blockIdx.x;  // 8192
  int t = threadIdx.x;   // 0..191, 192*4 = 768
  float4 v = ((const float4*)(x + (size_t)row * E_))[t];
  float s = v.x + v.y + v.z + v.w;
  float s2 = v.x * v.x + v.y * v.y + v.z * v.z + v.w * v.w;
  for (int off = 32; off; off >>= 1) {
    s += __shfl_xor(s, off, 64);
    s2 += __shfl_xor(s2, off, 64);
  }
  __shared__ float red[6];
  int lane = t & 63, wv = t >> 6;
  if (lane == 0) { red[wv] = s; red[3 + wv] = s2; }
  __syncthreads();
  s = red[0] + red[1] + red[2];
  s2 = red[3] + red[4] + red[5];
  float mu = s * (1.0f / E_);
  float var = s2 * (1.0f / E_) - mu * mu;
  float rstd = rsqrtf(var + 1e-5f);
  float4 gg = ((const float4*)g)[t];
  float4 bb = ((const float4*)bta)[t];
  ushort4 o;
  o.x = f2bf((v.x - mu) * rstd * gg.x + bb.x);
  o.y = f2bf((v.y - mu) * rstd * gg.y + bb.y);
  o.z = f2bf((v.z - mu) * rstd * gg.z + bb.z);
  o.w = f2bf((v.w - mu) * rstd * gg.w + bb.w);
  ((ushort4*)(xn + (size_t)row * E_))[t] = o;
}

// ---------------- GEMM  C = A @ W^T + bias ------------------------------------
// 2-phase prefetch + XCD swizzle + T2 LDS XOR-swizzle (both-sides, rule #21)
// EPI 0: scatter to Q(*0.125*log2e) [bh][n][d], K [bh][n][d], V^T [bh][d][n]
// EPI 1: dense fp32 [M][E]
template <int EPI>
__global__ __launch_bounds__(256) void k_gemm_bt(
    const unsigned short* __restrict__ A,   // [M][K] bf16
    const unsigned short* __restrict__ W,   // [Nf][K] bf16
    const float* __restrict__ bias,         // [Nf]
    unsigned short* __restrict__ oQ, unsigned short* __restrict__ oK,
    unsigned short* __restrict__ oVt, float* __restrict__ oF,
    int K, int Nf) {
  __shared__ unsigned short Al[2][128 * 64];
  __shared__ unsigned short Bl[2][128 * 64];
  // bijective XCD-aware block swizzle: contiguous logical tiles per XCD
  const int nbx = Nf >> 7;                  // 18 or 6
  const int nwg = nbx << 6;                 // *64 m-blocks; %8 == 0
  const int orig = blockIdx.y * nbx + blockIdx.x;
  const int id = (orig & 7) * (nwg >> 3) + (orig >> 3);
  const int n0 = (id % nbx) * 128, m0 = (id / nbx) * 128;
  const int tid = threadIdx.x;
  const int lane = tid & 63, wv = tid >> 6;
  const int wr = wv >> 1, wc = wv & 1;      // 2x2 waves of 64x64
  const int g = lane >> 4, l15 = lane & 15;
  f4_t acc[4][4] = {};

  auto stage = [&](int k0, int buf) {
#pragma unroll
    for (int i = 0; i < 4; ++i) {
      int e = (i * 256 + tid) * 8;          // element idx in 128x64 tile
      int r = e >> 6;
      int c = (e & 63) ^ swz(r);            // inverse-swizzled source column
      load_lds16(A + (size_t)(m0 + r) * K + (k0 + c), &Al[buf][e]);
      load_lds16(W + (size_t)(n0 + r) * K + (k0 + c), &Bl[buf][e]);
    }
  };

  stage(0, 0);
  __syncthreads();                          // drains vmcnt(0): tile 0 ready
  int cur = 0;

  for (int k0 = 0; k0 < K; k0 += 64) {
    if (k0 + 64 < K) stage(k0 + 64, cur ^ 1);  // prefetch next K-tile
    const unsigned short* Ac = Al[cur];
    const unsigned short* Bc = Bl[cur];
#pragma unroll
    for (int kk = 0; kk < 2; ++kk) {
      bf8_t af[4], bfr[4];
#pragma unroll
      for (int mi = 0; mi < 4; ++mi) {
        int ar = wr * 64 + mi * 16 + l15;
        af[mi] = *(const bf8_t*)&Ac[(ar * 64 + kk * 32 + g * 8) ^ swz(ar)];
      }
#pragma unroll
      for (int ni = 0; ni < 4; ++ni) {
        int br = wc * 64 + ni * 16 + l15;
        bfr[ni] = *(const bf8_t*)&Bc[(br * 64 + kk * 32 + g * 8) ^ swz(br)];
      }
#pragma unroll
      for (int mi = 0; mi < 4; ++mi)
#pragma unroll
        for (int ni = 0; ni < 4; ++ni)
          acc[mi][ni] = __builtin_amdgcn_mfma_f32_16x16x32_bf16(
              af[mi], bfr[ni], acc[mi][ni], 0, 0, 0);
    }
    __syncthreads();   // next tile landed; all waves done reading `cur`
    cur ^= 1;
  }

#pragma unroll
  for (int mi = 0; mi < 4; ++mi) {
#pragma unroll
    for (int ni = 0; ni < 4; ++ni) {
      int f = n0 + wc * 64 + ni * 16 + l15;
      float bs = bias[f];
#pragma unroll
      for (int i = 0; i < 4; ++i) {
        int m = m0 + wr * 64 + mi * 16 + g * 4 + i;
        float val = acc[mi][ni][i] + bs;
        if (EPI == 0) {
          int bb = m >> 10, n = m & 1023;
          int which = f / E_;
          int e2 = f - which * E_;
          int h = e2 >> 6, d = e2 & 63;
          size_t qk = (((size_t)bb * H_ + h) * N_ + n) * HD_ + d;
          if (which == 0) oQ[qk] = f2bf(val * 0.1803368801f);  // 0.125*log2(e)
          else if (which == 1) oK[qk] = f2bf(val);
          else oVt[(((size_t)bb * H_ + h) * HD_ + d) * N_ + n] = f2bf(val);
        } else {
          oF[(size_t)m * E_ + f] = val;
        }
      }
    }
  }
}

// ---------------- flash attention -------------------------------------------
// 2 q-tiles (128 rows) per block; 4 waves; KV tiles of 64; swapped-operand
// lane-local softmax; shuffle-free steady state (lazy max, deferred l-reduce).
__global__ __launch_bounds__(256) void k_attn(
    const unsigned short* __restrict__ Q,   // [bh][n][64], pre-scaled
    const unsigned short* __restrict__ Kb,  // [bh][n][64]
    const unsigned short* __restrict__ Vt,  // [bh][64][n]
    unsigned short* __restrict__ ctx) {     // [b][n][768]
  __shared__ unsigned short Kl[2][64 * 64];
  __shared__ unsigned short Vl[2][64 * 64];   // [d][k_local]
  __shared__ unsigned short Pl[4][2][16 * 64];  // per-wave P/O staging, a & b
  const int bh = blockIdx.x;   // 96
  const int qt = blockIdx.y;   // 8 (128-row pairs)
  const int tid = threadIdx.x;
  const int lane = tid & 63, wv = tid >> 6;
  const int g = lane >> 4, l15 = lane & 15;

  const unsigned short* Qp = Q + ((size_t)bh * N_ + qt * 128 + wv * 16) * HD_;
  bf8_t qfa[2], qfb[2];
#pragma unroll
  for (int kk = 0; kk < 2; ++kk) {
    qfa[kk] = *(const bf8_t*)&Qp[(size_t)l15 * HD_ + kk * 32 + g * 8];
    qfb[kk] = *(const bf8_t*)&Qp[(size_t)(64 + l15) * HD_ + kk * 32 + g * 8];
  }

  f4_t oa[4] = {}, ob[4] = {};   // O^T: col q=l15, rows d = di*16 + g*4 + i
  float mra = -1e30f, lra = 0.f; // per-lane running max / PARTIAL denom
  float mrb = -1e30f, lrb = 0.f;
  const unsigned short* Kbase = Kb + (size_t)bh * N_ * HD_;
  const unsigned short* Vbase = Vt + (size_t)bh * HD_ * N_;

  auto stage = [&](int t, int buf) {
#pragma unroll
    for (int i = 0; i < 2; ++i) {
      int e = (i * 256 + tid) * 8;          // 64x64 tile, 16B per lane
      int r = e >> 6;
      int c = (e & 63) ^ swz(r);            // inverse-swizzled source column
      load_lds16(Kbase + (size_t)(t * 64 + r) * HD_ + c, &Kl[buf][e]);
      load_lds16(Vbase + (size_t)r * N_ + (t * 64 + c), &Vl[buf][e]);
    }
  };

  stage(0, 0);
  __syncthreads();
  int cur = 0;
  unsigned short* Pwa = &Pl[wv][0][0];
  unsigned short* Pwb = &Pl[wv][1][0];

  for (int t = 0; t < 16; ++t) {
    if (t + 1 < 16) stage(t + 1, cur ^ 1);  // prefetch next tile
    const unsigned short* Klc = Kl[cur];
    const unsigned short* Vlc = Vl[cur];

    // S^T[kv][q] for both q-tiles: 16 independent MFMAs back-to-back
    f4_t sa[4] = {}, sb[4] = {};
    __builtin_amdgcn_s_setprio(1);
#pragma unroll
    for (int ni = 0; ni < 4; ++ni) {
      int krow = ni * 16 + l15;
#pragma unroll
      for (int kk = 0; kk < 2; ++kk) {
        bf8_t kf = *(const bf8_t*)&Klc[(krow * 64 + kk * 32 + g * 8) ^ swz(krow)];
        sa[ni] = __builtin_amdgcn_mfma_f32_16x16x32_bf16(kf, qfa[kk], sa[ni], 0, 0, 0);
        sb[ni] = __builtin_amdgcn_mfma_f32_16x16x32_bf16(kf, qfb[kk], sb[ni], 0, 0, 0);
      }
    }
    __builtin_amdgcn_s_setprio(0);

    // per-lane max trees (no shuffles in steady state)
    float ta0 = F3(sa[0][0], sa[0][1], sa[0][2]);
    float ta1 = F3(sa[0][3], sa[1][0], sa[1][1]);
    float ta2 = F3(sa[1][2], sa[1][3], sa[2][0]);
    float ta3 = F3(sa[2][1], sa[2][2], sa[2][3]);
    float ta4 = F3(sa[3][0], sa[3][1], sa[3][2]);
    float mxa = fmaxf(F3(F3(ta0, ta1, ta2), ta3, ta4), sa[3][3]);
    float tb0 = F3(sb[0][0], sb[0][1], sb[0][2]);
    float tb1 = F3(sb[0][3], sb[1][0], sb[1][1]);
    float tb2 = F3(sb[1][2], sb[1][3], sb[2][0]);
    float tb3 = F3(sb[2][1], sb[2][2], sb[2][3]);
    float tb4 = F3(sb[3][0], sb[3][1], sb[3][2]);
    float mxb = fmaxf(F3(F3(tb0, tb1, tb2), tb3, tb4), sb[3][3]);

    // lazy max: reduce + rescale only on breach (P bounded by 2^8)
    bool ok = (mxa - mra <= 8.0f) && (mxb - mrb <= 8.0f);
    if (!__all(ok)) {
      float Ma = fmaxf(mxa, __shfl_xor(mxa, 16, 64));
      Ma = fmaxf(Ma, __shfl_xor(Ma, 32, 64));
      float Mb = fmaxf(mxb, __shfl_xor(mxb, 16, 64));
      Mb = fmaxf(Mb, __shfl_xor(Mb, 32, 64));
      float mna = fmaxf(mra, Ma), mnb = fmaxf(mrb, Mb);
      float ala = exp2f(mra - mna), alb = exp2f(mrb - mnb);
      lra *= ala; lrb *= alb;
#pragma unroll
      for (int di = 0; di < 4; ++di)
#pragma unroll
        for (int i = 0; i < 4; ++i) { oa[di][i] *= ala; ob[di][i] *= alb; }
      mra = mna; mrb = mnb;
    }

    float ra = 0.f, rb = 0.f;
#pragma unroll
    for (int ni = 0; ni < 4; ++ni)
#pragma unroll
      for (int i = 0; i < 4; ++i) {
        float pa = exp2f(sa[ni][i] - mra);
        float pb = exp2f(sb[ni][i] - mrb);
        sa[ni][i] = pa; sb[ni][i] = pb;
        ra += pa; rb += pb;
      }
    lra += ra; lrb += rb;   // per-lane partials; reduced once in epilogue

    // P tiles, packed b64 writes, row-swizzled (separate buffers a/b)
#pragma unroll
    for (int ni = 0; ni < 4; ++ni) {
      int pe = l15 * 64 + ((ni * 16 + g * 4) ^ ((l15 & 7) << 3));
      uint2 pka, pkb;
      pka.x = cvt_pk_bf16(sa[ni][0], sa[ni][1]);
      pka.y = cvt_pk_bf16(sa[ni][2], sa[ni][3]);
      pkb.x = cvt_pk_bf16(sb[ni][0], sb[ni][1]);
      pkb.y = cvt_pk_bf16(sb[ni][2], sb[ni][3]);
      *(uint2*)&Pwa[pe] = pka;
      *(uint2*)&Pwb[pe] = pkb;
    }
    asm volatile("s_waitcnt lgkmcnt(0)" ::: "memory");
    __builtin_amdgcn_sched_barrier(0);

    // O^T += mfma(V, P) for both tiles
    __builtin_amdgcn_s_setprio(1);
#pragma unroll
    for (int kk = 0; kk < 2; ++kk) {
      int pe = l15 * 64 + ((kk * 32 + g * 8) ^ ((l15 & 7) << 3));
      bf8_t pfa = *(const bf8_t*)&Pwa[pe];
      bf8_t pfb = *(const bf8_t*)&Pwb[pe];
#pragma unroll
      for (int di = 0; di < 4; ++di) {
        int vrow = di * 16 + l15;
        bf8_t vf = *(const bf8_t*)&Vlc[(vrow * 64 + kk * 32 + g * 8) ^ swz(vrow)];
        oa[di] = __builtin_amdgcn_mfma_f32_16x16x32_bf16(vf, pfa, oa[di], 0, 0, 0);
        ob[di] = __builtin_amdgcn_mfma_f32_16x16x32_bf16(vf, pfb, ob[di], 0, 0, 0);
      }
    }
    __builtin_amdgcn_s_setprio(0);

    __syncthreads();  // prefetched tile landed; all waves done with `cur`
    cur ^= 1;
  }

  // epilogue: reduce per-lane partial denominators once
  lra += __shfl_xor(lra, 16, 64); lra += __shfl_xor(lra, 32, 64);
  lrb += __shfl_xor(lrb, 16, 64); lrb += __shfl_xor(lrb, 32, 64);
  float rinva = 1.0f / lra, rinvb = 1.0f / lrb;
#pragma unroll
  for (int di = 0; di < 4; ++di) {
    int oe = l15 * 64 + ((di * 16 + g * 4) ^ ((l15 & 7) << 3));
    uint2 pka, pkb;
    pka.x = cvt_pk_bf16(oa[di][0] * rinva, oa[di][1] * rinva);
    pka.y = cvt_pk_bf16(oa[di][2] * rinva, oa[di][3] * rinva);
    pkb.x = cvt_pk_bf16(ob[di][0] * rinvb, ob[di][1] * rinvb);
    pkb.y = cvt_pk_bf16(ob[di][2] * rinvb, ob[di][3] * rinvb);
    *(uint2*)&Pwa[oe] = pka;
    *(uint2*)&Pwb[oe] = pkb;
  }
  asm volatile("s_waitcnt lgkmcnt(0)" ::: "memory");
  __builtin_amdgcn_sched_barrier(0);

  const int bb = bh / H_, h = bh - bb * H_;
  const int rr = lane >> 2, cb = (lane & 3) * 16;
#pragma unroll
  for (int m2 = 0; m2 < 2; ++m2) {
    int e = rr * 64 + ((cb + 8 * m2) ^ ((rr & 7) << 3));
    bf8_t va = *(const bf8_t*)&Pwa[e];
    bf8_t vb = *(const bf8_t*)&Pwb[e];
    size_t rowa = (size_t)bb * N_ + qt * 128 + wv * 16 + rr;
    *(bf8_t*)(ctx + rowa * E_ + h * HD_ + cb + 8 * m2) = va;
    *(bf8_t*)(ctx + (rowa + 64) * E_ + h * HD_ + cb + 8 * m2) = vb;
  }
}

// ---------------- launch ----------------
extern "C" void kernel_launch(void* const* d_in, const int* in_sizes, int n_in,
                              void* d_out, int out_size, void* d_ws, size_t ws_size,
                              hipStream_t stream) {
  const float* x     = (const float*)d_in[0];
  const float* ln_g  = (const float*)d_in[1];
  const float* ln_b  = (const float*)d_in[2];
  const float* w_qkv = (const float*)d_in[3];
  const float* b_qkv = (const float*)d_in[4];
  const float* w_out = (const float*)d_in[5];
  const float* b_out = (const float*)d_in[6];
  float* out = (float*)d_out;

  char* ws = (char*)d_ws;
  const size_t SZ = (size_t)M_ * E_ * 2;  // 12.58 MB per bf16 activation
  unsigned short* xn    = (unsigned short*)(ws);
  unsigned short* qb    = (unsigned short*)(ws + SZ);
  unsigned short* kbuf  = (unsigned short*)(ws + 2 * SZ);
  unsigned short* vtb   = (unsigned short*)(ws + 3 * SZ);
  unsigned short* ctx   = (unsigned short*)(ws + 4 * SZ);
  unsigned short* wqkvb = (unsigned short*)(ws + 5 * SZ);
  unsigned short* woutb = (unsigned short*)(ws + 5 * SZ + (size_t)3 * E_ * E_ * 2);

  int n1 = 3 * E_ * E_ / 4;
  k_cast_bf16<<<(n1 + 255) / 256, 256, 0, stream>>>(w_qkv, wqkvb, n1);
  int n2 = E_ * E_ / 4;
  k_cast_bf16<<<(n2 + 255) / 256, 256, 0, stream>>>(w_out, woutb, n2);

  k_ln<<<M_, 192, 0, stream>>>(x, ln_g, ln_b, xn);

  k_gemm_bt<0><<<dim3(18, 64), 256, 0, stream>>>(xn, wqkvb, b_qkv, qb, kbuf, vtb,
                                                 nullptr, E_, 3 * E_);
  k_attn<<<dim3(96, 8), 256, 0, stream>>>(qb, kbuf, vtb, ctx);
  k_gemm_bt<1><<<dim3(6, 64), 256, 0, stream>>>(ctx, woutb, b_out, nullptr, nullptr,
                                                nullptr, out, E_, E_);
}

// Round 8
// 155.460 us; speedup vs baseline: 1.0684x; 1.0684x over previous
//
#include <hip/hip_runtime.h>
#include <hip/hip_bf16.h>
#include <stdint.h>

#define B_ 8
#define N_ 1024
#define E_ 768
#define H_ 12
#define HD_ 64
#define M_ (B_ * N_)   // 8192 rows

typedef __attribute__((ext_vector_type(8))) short bf8_t;   // 8 x bf16 (4 VGPR)
typedef __attribute__((ext_vector_type(4))) float f4_t;    // 4 x f32

__device__ __forceinline__ unsigned short f2bf(float f) {
  unsigned u = __builtin_bit_cast(unsigned, f);
  unsigned r = (u + 0x7fffu + ((u >> 16) & 1u)) >> 16;  // RNE
  return (unsigned short)r;
}

__device__ __forceinline__ unsigned cvt_pk_bf16(float lo, float hi) {
  unsigned r;
  asm("v_cvt_pk_bf16_f32 %0, %1, %2" : "=v"(r) : "v"(lo), "v"(hi));
  return r;
}

// single-instruction exp2 (libm exp2f lowers to an __ocml call without
// fast-math; v_exp_f32 is the hardware op, denorm-flush is fine here)
__device__ __forceinline__ float exp2_hw(float x) {
  float r;
  asm("v_exp_f32 %0, %1" : "=v"(r) : "v"(x));
  return r;
}

__device__ __forceinline__ void load_lds16(const void* g, void* l) {
  __builtin_amdgcn_global_load_lds(
      (__attribute__((address_space(1))) void*)(g),
      (__attribute__((address_space(3))) void*)(l), 16, 0, 0);
}

// XOR swizzle on the 8-element (16B) chunk index within a 64-elem (128B) row.
__device__ __forceinline__ int swz(int row) {
  return ((row ^ (row >> 3)) & 7) << 3;
}

#define F3(a, b, c) fmaxf(fmaxf((a), (b)), (c))   // fuses to v_max3_f32

// ---------------- weight fp32 -> bf16 cast (vectorized) ----------------
__global__ void k_cast_bf16(const float* __restrict__ in,
                            unsigned short* __restrict__ out, int n4) {
  int i = blockIdx.x * blockDim.x + threadIdx.x;
  if (i < n4) {
    float4 v = ((const float4*)in)[i];
    ushort4 o;
    o.x = f2bf(v.x); o.y = f2bf(v.y); o.z = f2bf(v.z); o.w = f2bf(v.w);
    ((ushort4*)out)[i] = o;
  }
}

// ---------------- LayerNorm -> bf16 (float4 loads, ushort4 stores) ----------
__global__ __launch_bounds__(192) void k_ln(const float* __restrict__ x,
                                            const float* __restrict__ g,
                                            const float* __restrict__ bta,
                                            unsigned short* __restrict__ xn) {
  int row = blockIdx.x;  // 8192
  int t = threadIdx.x;   // 0..191, 192*4 = 768
  float4 v = ((const float4*)(x + (size_t)row * E_))[t];
  float s = v.x + v.y + v.z + v.w;
  float s2 = v.x * v.x + v.y * v.y + v.z * v.z + v.w * v.w;
  for (int off = 32; off; off >>= 1) {
    s += __shfl_xor(s, off, 64);
    s2 += __shfl_xor(s2, off, 64);
  }
  __shared__ float red[6];
  int lane = t & 63, wv = t >> 6;
  if (lane == 0) { red[wv] = s; red[3 + wv] = s2; }
  __syncthreads();
  s = red[0] + red[1] + red[2];
  s2 = red[3] + red[4] + red[5];
  float mu = s * (1.0f / E_);
  float var = s2 * (1.0f / E_) - mu * mu;
  float rstd = rsqrtf(var + 1e-5f);
  float4 gg = ((const float4*)g)[t];
  float4 bb = ((const float4*)bta)[t];
  ushort4 o;
  o.x = f2bf((v.x - mu) * rstd * gg.x + bb.x);
  o.y = f2bf((v.y - mu) * rstd * gg.y + bb.y);
  o.z = f2bf((v.z - mu) * rstd * gg.z + bb.z);
  o.w = f2bf((v.w - mu) * rstd * gg.w + bb.w);
  ((ushort4*)(xn + (size_t)row * E_))[t] = o;
}

// ---------------- GEMM  C = A @ W^T + bias ------------------------------------
// 2-phase prefetch + XCD swizzle + T2 LDS XOR-swizzle (both-sides, rule #21)
// EPI 0: scatter to Q(*0.125*log2e) [bh][n][d], K [bh][n][d], V^T [bh][d][n]
// EPI 1: dense fp32 [M][E]
template <int EPI>
__global__ __launch_bounds__(256) void k_gemm_bt(
    const unsigned short* __restrict__ A,   // [M][K] bf16
    const unsigned short* __restrict__ W,   // [Nf][K] bf16
    const float* __restrict__ bias,         // [Nf]
    unsigned short* __restrict__ oQ, unsigned short* __restrict__ oK,
    unsigned short* __restrict__ oVt, float* __restrict__ oF,
    int K, int Nf) {
  __shared__ unsigned short Al[2][128 * 64];
  __shared__ unsigned short Bl[2][128 * 64];
  // bijective XCD-aware block swizzle: contiguous logical tiles per XCD
  const int nbx = Nf >> 7;                  // 18 or 6
  const int nwg = nbx << 6;                 // *64 m-blocks; %8 == 0
  const int orig = blockIdx.y * nbx + blockIdx.x;
  const int id = (orig & 7) * (nwg >> 3) + (orig >> 3);
  const int n0 = (id % nbx) * 128, m0 = (id / nbx) * 128;
  const int tid = threadIdx.x;
  const int lane = tid & 63, wv = tid >> 6;
  const int wr = wv >> 1, wc = wv & 1;      // 2x2 waves of 64x64
  const int g = lane >> 4, l15 = lane & 15;
  f4_t acc[4][4] = {};

  auto stage = [&](int k0, int buf) {
#pragma unroll
    for (int i = 0; i < 4; ++i) {
      int e = (i * 256 + tid) * 8;          // element idx in 128x64 tile
      int r = e >> 6;
      int c = (e & 63) ^ swz(r);            // inverse-swizzled source column
      load_lds16(A + (size_t)(m0 + r) * K + (k0 + c), &Al[buf][e]);
      load_lds16(W + (size_t)(n0 + r) * K + (k0 + c), &Bl[buf][e]);
    }
  };

  stage(0, 0);
  __syncthreads();                          // drains vmcnt(0): tile 0 ready
  int cur = 0;

  for (int k0 = 0; k0 < K; k0 += 64) {
    if (k0 + 64 < K) stage(k0 + 64, cur ^ 1);  // prefetch next K-tile
    const unsigned short* Ac = Al[cur];
    const unsigned short* Bc = Bl[cur];
#pragma unroll
    for (int kk = 0; kk < 2; ++kk) {
      bf8_t af[4], bfr[4];
#pragma unroll
      for (int mi = 0; mi < 4; ++mi) {
        int ar = wr * 64 + mi * 16 + l15;
        af[mi] = *(const bf8_t*)&Ac[(ar * 64 + kk * 32 + g * 8) ^ swz(ar)];
      }
#pragma unroll
      for (int ni = 0; ni < 4; ++ni) {
        int br = wc * 64 + ni * 16 + l15;
        bfr[ni] = *(const bf8_t*)&Bc[(br * 64 + kk * 32 + g * 8) ^ swz(br)];
      }
#pragma unroll
      for (int mi = 0; mi < 4; ++mi)
#pragma unroll
        for (int ni = 0; ni < 4; ++ni)
          acc[mi][ni] = __builtin_amdgcn_mfma_f32_16x16x32_bf16(
              af[mi], bfr[ni], acc[mi][ni], 0, 0, 0);
    }
    __syncthreads();   // next tile landed; all waves done reading `cur`
    cur ^= 1;
  }

#pragma unroll
  for (int mi = 0; mi < 4; ++mi) {
#pragma unroll
    for (int ni = 0; ni < 4; ++ni) {
      int f = n0 + wc * 64 + ni * 16 + l15;
      float bs = bias[f];
#pragma unroll
      for (int i = 0; i < 4; ++i) {
        int m = m0 + wr * 64 + mi * 16 + g * 4 + i;
        float val = acc[mi][ni][i] + bs;
        if (EPI == 0) {
          int bb = m >> 10, n = m & 1023;
          int which = f / E_;
          int e2 = f - which * E_;
          int h = e2 >> 6, d = e2 & 63;
          size_t qk = (((size_t)bb * H_ + h) * N_ + n) * HD_ + d;
          if (which == 0) oQ[qk] = f2bf(val * 0.1803368801f);  // 0.125*log2(e)
          else if (which == 1) oK[qk] = f2bf(val);
          else oVt[(((size_t)bb * H_ + h) * HD_ + d) * N_ + n] = f2bf(val);
        } else {
          oF[(size_t)m * E_ + f] = val;
        }
      }
    }
  }
}

// ---------------- flash attention -------------------------------------------
// 1 q-tile (64 rows) per block; 4 waves x 16 q-rows; KV tiles of 64.
// Swapped-operand lane-local softmax; shuffle-free steady state (lazy max,
// per-lane partial denom); hardware exp2; LDS = 40960 B (4 blocks/CU).
__global__ __launch_bounds__(256) void k_attn(
    const unsigned short* __restrict__ Q,   // [bh][n][64], pre-scaled
    const unsigned short* __restrict__ Kb,  // [bh][n][64]
    const unsigned short* __restrict__ Vt,  // [bh][64][n]
    unsigned short* __restrict__ ctx) {     // [b][n][768]
  __shared__ unsigned short Kl[2][64 * 64];
  __shared__ unsigned short Vl[2][64 * 64];  // [d][k_local]
  __shared__ unsigned short Pl[4][16 * 64];  // per-wave P / O staging [q][*]
  const int bh = blockIdx.x;   // 96
  const int qt = blockIdx.y;   // 16
  const int tid = threadIdx.x;
  const int lane = tid & 63, wv = tid >> 6;
  const int g = lane >> 4, l15 = lane & 15;

  const unsigned short* Qp = Q + ((size_t)bh * N_ + qt * 64 + wv * 16) * HD_;
  bf8_t qf[2];
#pragma unroll
  for (int kk = 0; kk < 2; ++kk)
    qf[kk] = *(const bf8_t*)&Qp[(size_t)l15 * HD_ + kk * 32 + g * 8];

  f4_t o[4] = {};                 // O^T: col q=l15, rows d = di*16 + g*4 + i
  float mrow = -1e30f, lrow = 0.f;  // per-lane running max / PARTIAL denom
  const unsigned short* Kbase = Kb + (size_t)bh * N_ * HD_;
  const unsigned short* Vbase = Vt + (size_t)bh * HD_ * N_;

  auto stage = [&](int t, int buf) {
#pragma unroll
    for (int i = 0; i < 2; ++i) {
      int e = (i * 256 + tid) * 8;          // 64x64 tile, 16B per lane
      int r = e >> 6;
      int c = (e & 63) ^ swz(r);            // inverse-swizzled source column
      load_lds16(Kbase + (size_t)(t * 64 + r) * HD_ + c, &Kl[buf][e]);
      load_lds16(Vbase + (size_t)r * N_ + (t * 64 + c), &Vl[buf][e]);
    }
  };

  stage(0, 0);
  __syncthreads();
  int cur = 0;
  unsigned short* Pw = &Pl[wv][0];

  for (int t = 0; t < 16; ++t) {
    if (t + 1 < 16) stage(t + 1, cur ^ 1);  // prefetch next tile
    const unsigned short* Klc = Kl[cur];
    const unsigned short* Vlc = Vl[cur];

    // S^T[kv][q]: s[ni] holds kv = ni*16 + g*4 + i  for q = l15 (exp2 domain)
    f4_t s[4] = {};
    __builtin_amdgcn_s_setprio(1);
#pragma unroll
    for (int ni = 0; ni < 4; ++ni) {
      int krow = ni * 16 + l15;
#pragma unroll
      for (int kk = 0; kk < 2; ++kk) {
        bf8_t kf = *(const bf8_t*)&Klc[(krow * 64 + kk * 32 + g * 8) ^ swz(krow)];
        s[ni] = __builtin_amdgcn_mfma_f32_16x16x32_bf16(kf, qf[kk], s[ni], 0, 0, 0);
      }
    }
    __builtin_amdgcn_s_setprio(0);

    // per-lane max tree (no shuffles in steady state)
    float t0 = F3(s[0][0], s[0][1], s[0][2]);
    float t1 = F3(s[0][3], s[1][0], s[1][1]);
    float t2 = F3(s[1][2], s[1][3], s[2][0]);
    float t3 = F3(s[2][1], s[2][2], s[2][3]);
    float t4 = F3(s[3][0], s[3][1], s[3][2]);
    float mx = fmaxf(F3(F3(t0, t1, t2), t3, t4), s[3][3]);

    // lazy max: reduce + rescale only on breach (P bounded by 2^8)
    if (!__all(mx - mrow <= 8.0f)) {
      float Mx = fmaxf(mx, __shfl_xor(mx, 16, 64));
      Mx = fmaxf(Mx, __shfl_xor(Mx, 32, 64));
      float mnew = fmaxf(mrow, Mx);
      float al = exp2_hw(mrow - mnew);
      lrow *= al;
#pragma unroll
      for (int di = 0; di < 4; ++di)
#pragma unroll
        for (int i = 0; i < 4; ++i) o[di][i] *= al;
      mrow = mnew;
    }

    // exp (hardware, independent ops) + tree-sum (depth 4, reassociated)
    float p0  = exp2_hw(s[0][0] - mrow), p1  = exp2_hw(s[0][1] - mrow);
    float p2  = exp2_hw(s[0][2] - mrow), p3  = exp2_hw(s[0][3] - mrow);
    float p4  = exp2_hw(s[1][0] - mrow), p5  = exp2_hw(s[1][1] - mrow);
    float p6  = exp2_hw(s[1][2] - mrow), p7  = exp2_hw(s[1][3] - mrow);
    float p8  = exp2_hw(s[2][0] - mrow), p9  = exp2_hw(s[2][1] - mrow);
    float p10 = exp2_hw(s[2][2] - mrow), p11 = exp2_hw(s[2][3] - mrow);
    float p12 = exp2_hw(s[3][0] - mrow), p13 = exp2_hw(s[3][1] - mrow);
    float p14 = exp2_hw(s[3][2] - mrow), p15 = exp2_hw(s[3][3] - mrow);
    float a0 = p0 + p1, a1 = p2 + p3, a2 = p4 + p5, a3 = p6 + p7;
    float a4 = p8 + p9, a5 = p10 + p11, a6 = p12 + p13, a7 = p14 + p15;
    float b0 = a0 + a1, b1 = a2 + a3, b2 = a4 + a5, b3 = a6 + a7;
    lrow += (b0 + b1) + (b2 + b3);   // per-lane partial; reduced in epilogue

    // P[q][kv] wave-private, packed b64 writes, row-swizzled
    {
      uint2 pk;
      pk.x = cvt_pk_bf16(p0, p1);   pk.y = cvt_pk_bf16(p2, p3);
      *(uint2*)&Pw[l15 * 64 + ((0 * 16 + g * 4) ^ ((l15 & 7) << 3))] = pk;
      pk.x = cvt_pk_bf16(p4, p5);   pk.y = cvt_pk_bf16(p6, p7);
      *(uint2*)&Pw[l15 * 64 + ((1 * 16 + g * 4) ^ ((l15 & 7) << 3))] = pk;
      pk.x = cvt_pk_bf16(p8, p9);   pk.y = cvt_pk_bf16(p10, p11);
      *(uint2*)&Pw[l15 * 64 + ((2 * 16 + g * 4) ^ ((l15 & 7) << 3))] = pk;
      pk.x = cvt_pk_bf16(p12, p13); pk.y = cvt_pk_bf16(p14, p15);
      *(uint2*)&Pw[l15 * 64 + ((3 * 16 + g * 4) ^ ((l15 & 7) << 3))] = pk;
    }
    asm volatile("s_waitcnt lgkmcnt(0)" ::: "memory");
    __builtin_amdgcn_sched_barrier(0);

    // O^T += mfma(V, P): A = V^T rows (d), B = P rows (q = l15)
    __builtin_amdgcn_s_setprio(1);
#pragma unroll
    for (int kk = 0; kk < 2; ++kk) {
      bf8_t pf = *(const bf8_t*)&Pw[l15 * 64 + ((kk * 32 + g * 8) ^ ((l15 & 7) << 3))];
#pragma unroll
      for (int di = 0; di < 4; ++di) {
        int vrow = di * 16 + l15;
        bf8_t vf = *(const bf8_t*)&Vlc[(vrow * 64 + kk * 32 + g * 8) ^ swz(vrow)];
        o[di] = __builtin_amdgcn_mfma_f32_16x16x32_bf16(vf, pf, o[di], 0, 0, 0);
      }
    }
    __builtin_amdgcn_s_setprio(0);

    __syncthreads();  // prefetched tile landed; all waves done with `cur`
    cur ^= 1;
  }

  // epilogue: reduce per-lane partial denominator once
  lrow += __shfl_xor(lrow, 16, 64);
  lrow += __shfl_xor(lrow, 32, 64);
  float rinv = 1.0f / lrow;
#pragma unroll
  for (int di = 0; di < 4; ++di) {
    uint2 pk;
    pk.x = cvt_pk_bf16(o[di][0] * rinv, o[di][1] * rinv);
    pk.y = cvt_pk_bf16(o[di][2] * rinv, o[di][3] * rinv);
    int oe = l15 * 64 + ((di * 16 + g * 4) ^ ((l15 & 7) << 3));
    *(uint2*)&Pw[oe] = pk;
  }
  asm volatile("s_waitcnt lgkmcnt(0)" ::: "memory");
  __builtin_amdgcn_sched_barrier(0);

  const int bb = bh / H_, h = bh - bb * H_;
  const int rr = lane >> 2, cb = (lane & 3) * 16;
#pragma unroll
  for (int m2 = 0; m2 < 2; ++m2) {
    int e = rr * 64 + ((cb + 8 * m2) ^ ((rr & 7) << 3));
    bf8_t val = *(const bf8_t*)&Pw[e];
    unsigned short* dst =
        ctx + ((size_t)bb * N_ + qt * 64 + wv * 16 + rr) * E_ + h * HD_ + cb + 8 * m2;
    *(bf8_t*)dst = val;
  }
}

// ---------------- launch ----------------
extern "C" void kernel_launch(void* const* d_in, const int* in_sizes, int n_in,
                              void* d_out, int out_size, void* d_ws, size_t ws_size,
                              hipStream_t stream) {
  const float* x     = (const float*)d_in[0];
  const float* ln_g  = (const float*)d_in[1];
  const float* ln_b  = (const float*)d_in[2];
  const float* w_qkv = (const float*)d_in[3];
  const float* b_qkv = (const float*)d_in[4];
  const float* w_out = (const float*)d_in[5];
  const float* b_out = (const float*)d_in[6];
  float* out = (float*)d_out;

  char* ws = (char*)d_ws;
  const size_t SZ = (size_t)M_ * E_ * 2;  // 12.58 MB per bf16 activation
  unsigned short* xn    = (unsigned short*)(ws);
  unsigned short* qb    = (unsigned short*)(ws + SZ);
  unsigned short* kbuf  = (unsigned short*)(ws + 2 * SZ);
  unsigned short* vtb   = (unsigned short*)(ws + 3 * SZ);
  unsigned short* ctx   = (unsigned short*)(ws + 4 * SZ);
  unsigned short* wqkvb = (unsigned short*)(ws + 5 * SZ);
  unsigned short* woutb = (unsigned short*)(ws + 5 * SZ + (size_t)3 * E_ * E_ * 2);

  int n1 = 3 * E_ * E_ / 4;
  k_cast_bf16<<<(n1 + 255) / 256, 256, 0, stream>>>(w_qkv, wqkvb, n1);
  int n2 = E_ * E_ / 4;
  k_cast_bf16<<<(n2 + 255) / 256, 256, 0, stream>>>(w_out, woutb, n2);

  k_ln<<<M_, 192, 0, stream>>>(x, ln_g, ln_b, xn);

  k_gemm_bt<0><<<dim3(18, 64), 256, 0, stream>>>(xn, wqkvb, b_qkv, qb, kbuf, vtb,
                                                 nullptr, E_, 3 * E_);
  k_attn<<<dim3(96, 16), 256, 0, stream>>>(qb, kbuf, vtb, ctx);
  k_gemm_bt<1><<<dim3(6, 64), 256, 0, stream>>>(ctx, woutb, b_out, nullptr, nullptr,
                                                nullptr, out, E_, E_);
}

// Round 9
// 154.852 us; speedup vs baseline: 1.0726x; 1.0039x over previous
//
#include <hip/hip_runtime.h>
#include <hip/hip_bf16.h>
#include <stdint.h>

#define B_ 8
#define N_ 1024
#define E_ 768
#define H_ 12
#define HD_ 64
#define M_ (B_ * N_)   // 8192 rows

typedef __attribute__((ext_vector_type(8))) short bf8_t;   // 8 x bf16 (4 VGPR)
typedef __attribute__((ext_vector_type(4))) float f4_t;    // 4 x f32

__device__ __forceinline__ unsigned short f2bf(float f) {
  unsigned u = __builtin_bit_cast(unsigned, f);
  unsigned r = (u + 0x7fffu + ((u >> 16) & 1u)) >> 16;  // RNE
  return (unsigned short)r;
}

__device__ __forceinline__ unsigned cvt_pk_bf16(float lo, float hi) {
  unsigned r;
  asm("v_cvt_pk_bf16_f32 %0, %1, %2" : "=v"(r) : "v"(lo), "v"(hi));
  return r;
}

// single-instruction exp2 (libm exp2f lowers to an __ocml call without
// fast-math; v_exp_f32 is the hardware op, denorm-flush is fine here)
__device__ __forceinline__ float exp2_hw(float x) {
  float r;
  asm("v_exp_f32 %0, %1" : "=v"(r) : "v"(x));
  return r;
}

__device__ __forceinline__ void load_lds16(const void* g, void* l) {
  __builtin_amdgcn_global_load_lds(
      (__attribute__((address_space(1))) void*)(g),
      (__attribute__((address_space(3))) void*)(l), 16, 0, 0);
}

// counted wait: stage(t+1)'s loads stay in flight across the barrier (T4)
#define WAITV(N)                                        \
  asm volatile("s_waitcnt vmcnt(" #N ")" ::: "memory"); \
  __builtin_amdgcn_sched_barrier(0);                    \
  __builtin_amdgcn_s_barrier();                         \
  __builtin_amdgcn_sched_barrier(0);

#define BAR2()                          \
  __builtin_amdgcn_sched_barrier(0);    \
  __builtin_amdgcn_s_barrier();         \
  __builtin_amdgcn_sched_barrier(0);

// XOR swizzle on the 8-element (16B) chunk index within a 64-elem (128B) row.
__device__ __forceinline__ int swz(int row) {
  return ((row ^ (row >> 3)) & 7) << 3;
}

#define F3(a, b, c) fmaxf(fmaxf((a), (b)), (c))   // fuses to v_max3_f32

// ---------------- weight fp32 -> bf16 cast (vectorized) ----------------
__global__ void k_cast_bf16(const float* __restrict__ in,
                            unsigned short* __restrict__ out, int n4) {
  int i = blockIdx.x * blockDim.x + threadIdx.x;
  if (i < n4) {
    float4 v = ((const float4*)in)[i];
    ushort4 o;
    o.x = f2bf(v.x); o.y = f2bf(v.y); o.z = f2bf(v.z); o.w = f2bf(v.w);
    ((ushort4*)out)[i] = o;
  }
}

// ---------------- LayerNorm -> bf16 (float4 loads, ushort4 stores) ----------
__global__ __launch_bounds__(192) void k_ln(const float* __restrict__ x,
                                            const float* __restrict__ g,
                                            const float* __restrict__ bta,
                                            unsigned short* __restrict__ xn) {
  int row = blockIdx.x;  // 8192
  int t = threadIdx.x;   // 0..191, 192*4 = 768
  float4 v = ((const float4*)(x + (size_t)row * E_))[t];
  float s = v.x + v.y + v.z + v.w;
  float s2 = v.x * v.x + v.y * v.y + v.z * v.z + v.w * v.w;
  for (int off = 32; off; off >>= 1) {
    s += __shfl_xor(s, off, 64);
    s2 += __shfl_xor(s2, off, 64);
  }
  __shared__ float red[6];
  int lane = t & 63, wv = t >> 6;
  if (lane == 0) { red[wv] = s; red[3 + wv] = s2; }
  __syncthreads();
  s = red[0] + red[1] + red[2];
  s2 = red[3] + red[4] + red[5];
  float mu = s * (1.0f / E_);
  float var = s2 * (1.0f / E_) - mu * mu;
  float rstd = rsqrtf(var + 1e-5f);
  float4 gg = ((const float4*)g)[t];
  float4 bb = ((const float4*)bta)[t];
  ushort4 o;
  o.x = f2bf((v.x - mu) * rstd * gg.x + bb.x);
  o.y = f2bf((v.y - mu) * rstd * gg.y + bb.y);
  o.z = f2bf((v.z - mu) * rstd * gg.z + bb.z);
  o.w = f2bf((v.w - mu) * rstd * gg.w + bb.w);
  ((ushort4*)(xn + (size_t)row * E_))[t] = o;
}

// ---------------- GEMM  C = A @ W^T + bias ------------------------------------
// 2-buffer pipeline, counted vmcnt (T4), XCD swizzle (T1), LDS XOR-swizzle (T2)
// EPI 0: scatter to Q(*0.125*log2e) [bh][n][d], K [bh][n][d], V^T [bh][d][n]
// EPI 1: dense fp32 [M][E]
template <int EPI>
__global__ __launch_bounds__(256) void k_gemm_bt(
    const unsigned short* __restrict__ A,   // [M][K] bf16
    const unsigned short* __restrict__ W,   // [Nf][K] bf16
    const float* __restrict__ bias,         // [Nf]
    unsigned short* __restrict__ oQ, unsigned short* __restrict__ oK,
    unsigned short* __restrict__ oVt, float* __restrict__ oF,
    int K, int Nf) {
  __shared__ unsigned short Al[2][128 * 64];
  __shared__ unsigned short Bl[2][128 * 64];
  // bijective XCD-aware block swizzle: contiguous logical tiles per XCD
  const int nbx = Nf >> 7;                  // 18 or 6
  const int nwg = nbx << 6;                 // *64 m-blocks; %8 == 0
  const int orig = blockIdx.y * nbx + blockIdx.x;
  const int id = (orig & 7) * (nwg >> 3) + (orig >> 3);
  const int n0 = (id % nbx) * 128, m0 = (id / nbx) * 128;
  const int tid = threadIdx.x;
  const int lane = tid & 63, wv = tid >> 6;
  const int wr = wv >> 1, wc = wv & 1;      // 2x2 waves of 64x64
  const int g = lane >> 4, l15 = lane & 15;
  f4_t acc[4][4] = {};

  auto stage = [&](int k0, int buf) {       // 8 loads / wave
#pragma unroll
    for (int i = 0; i < 4; ++i) {
      int e = (i * 256 + tid) * 8;          // element idx in 128x64 tile
      int r = e >> 6;
      int c = (e & 63) ^ swz(r);            // inverse-swizzled source column
      load_lds16(A + (size_t)(m0 + r) * K + (k0 + c), &Al[buf][e]);
      load_lds16(W + (size_t)(n0 + r) * K + (k0 + c), &Bl[buf][e]);
    }
  };

  const int NT = K >> 6;                    // 12
  stage(0, 0);
  stage(64, 1);

  for (int t = 0; t < NT; ++t) {
    const int cur = t & 1;
    // tile t ready; stage(t+1)'s 8 loads stay outstanding across the barrier
    if (t + 1 < NT) { WAITV(8); } else { WAITV(0); }
    const unsigned short* Ac = Al[cur];
    const unsigned short* Bc = Bl[cur];
#pragma unroll
    for (int kk = 0; kk < 2; ++kk) {
      bf8_t af[4], bfr[4];
#pragma unroll
      for (int mi = 0; mi < 4; ++mi) {
        int ar = wr * 64 + mi * 16 + l15;
        af[mi] = *(const bf8_t*)&Ac[(ar * 64 + kk * 32 + g * 8) ^ swz(ar)];
      }
#pragma unroll
      for (int ni = 0; ni < 4; ++ni) {
        int br = wc * 64 + ni * 16 + l15;
        bfr[ni] = *(const bf8_t*)&Bc[(br * 64 + kk * 32 + g * 8) ^ swz(br)];
      }
#pragma unroll
      for (int mi = 0; mi < 4; ++mi)
#pragma unroll
        for (int ni = 0; ni < 4; ++ni)
          acc[mi][ni] = __builtin_amdgcn_mfma_f32_16x16x32_bf16(
              af[mi], bfr[ni], acc[mi][ni], 0, 0, 0);
    }
    // all waves done READING buf[cur] (ds_reads completed before their MFMAs)
    BAR2();
    if (t + 2 < NT) stage((t + 2) << 6, cur);  // overwrite freed buffer
  }

#pragma unroll
  for (int mi = 0; mi < 4; ++mi) {
#pragma unroll
    for (int ni = 0; ni < 4; ++ni) {
      int f = n0 + wc * 64 + ni * 16 + l15;
      float bs = bias[f];
#pragma unroll
      for (int i = 0; i < 4; ++i) {
        int m = m0 + wr * 64 + mi * 16 + g * 4 + i;
        float val = acc[mi][ni][i] + bs;
        if (EPI == 0) {
          int bb = m >> 10, n = m & 1023;
          int which = f / E_;
          int e2 = f - which * E_;
          int h = e2 >> 6, d = e2 & 63;
          size_t qk = (((size_t)bb * H_ + h) * N_ + n) * HD_ + d;
          if (which == 0) oQ[qk] = f2bf(val * 0.1803368801f);  // 0.125*log2(e)
          else if (which == 1) oK[qk] = f2bf(val);
          else oVt[(((size_t)bb * H_ + h) * HD_ + d) * N_ + n] = f2bf(val);
        } else {
          oF[(size_t)m * E_ + f] = val;
        }
      }
    }
  }
}

// ---------------- flash attention -------------------------------------------
// 1 q-tile (64 rows) per block; 4 waves x 16 q-rows; KV tiles of 64.
// Swapped-operand lane-local softmax; lazy max; per-lane partial denom;
// hardware exp2; counted-vmcnt pipeline (T4). LDS 40960 B (4 blocks/CU).
__global__ __launch_bounds__(256) void k_attn(
    const unsigned short* __restrict__ Q,   // [bh][n][64], pre-scaled
    const unsigned short* __restrict__ Kb,  // [bh][n][64]
    const unsigned short* __restrict__ Vt,  // [bh][64][n]
    unsigned short* __restrict__ ctx) {     // [b][n][768]
  __shared__ unsigned short Kl[2][64 * 64];
  __shared__ unsigned short Vl[2][64 * 64];  // [d][k_local]
  __shared__ unsigned short Pl[4][16 * 64];  // per-wave P / O staging [q][*]
  const int bh = blockIdx.x;   // 96
  const int qt = blockIdx.y;   // 16
  const int tid = threadIdx.x;
  const int lane = tid & 63, wv = tid >> 6;
  const int g = lane >> 4, l15 = lane & 15;

  const unsigned short* Qp = Q + ((size_t)bh * N_ + qt * 64 + wv * 16) * HD_;
  bf8_t qf[2];
#pragma unroll
  for (int kk = 0; kk < 2; ++kk)
    qf[kk] = *(const bf8_t*)&Qp[(size_t)l15 * HD_ + kk * 32 + g * 8];

  f4_t o[4] = {};                 // O^T: col q=l15, rows d = di*16 + g*4 + i
  float mrow = -1e30f, lrow = 0.f;  // per-lane running max / PARTIAL denom
  const unsigned short* Kbase = Kb + (size_t)bh * N_ * HD_;
  const unsigned short* Vbase = Vt + (size_t)bh * HD_ * N_;

  auto stage = [&](int t, int buf) {        // 4 loads / wave
#pragma unroll
    for (int i = 0; i < 2; ++i) {
      int e = (i * 256 + tid) * 8;          // 64x64 tile, 16B per lane
      int r = e >> 6;
      int c = (e & 63) ^ swz(r);            // inverse-swizzled source column
      load_lds16(Kbase + (size_t)(t * 64 + r) * HD_ + c, &Kl[buf][e]);
      load_lds16(Vbase + (size_t)r * N_ + (t * 64 + c), &Vl[buf][e]);
    }
  };

  stage(0, 0);
  stage(1, 1);
  unsigned short* Pw = &Pl[wv][0];

  for (int t = 0; t < 16; ++t) {
    const int cur = t & 1;
    if (t + 1 < 16) { WAITV(4); } else { WAITV(0); }
    const unsigned short* Klc = Kl[cur];
    const unsigned short* Vlc = Vl[cur];

    // S^T[kv][q]: s[ni] holds kv = ni*16 + g*4 + i  for q = l15 (exp2 domain)
    f4_t s[4] = {};
    __builtin_amdgcn_s_setprio(1);
#pragma unroll
    for (int ni = 0; ni < 4; ++ni) {
      int krow = ni * 16 + l15;
#pragma unroll
      for (int kk = 0; kk < 2; ++kk) {
        bf8_t kf = *(const bf8_t*)&Klc[(krow * 64 + kk * 32 + g * 8) ^ swz(krow)];
        s[ni] = __builtin_amdgcn_mfma_f32_16x16x32_bf16(kf, qf[kk], s[ni], 0, 0, 0);
      }
    }
    __builtin_amdgcn_s_setprio(0);

    // per-lane max tree (no shuffles in steady state)
    float t0 = F3(s[0][0], s[0][1], s[0][2]);
    float t1 = F3(s[0][3], s[1][0], s[1][1]);
    float t2 = F3(s[1][2], s[1][3], s[2][0]);
    float t3 = F3(s[2][1], s[2][2], s[2][3]);
    float t4 = F3(s[3][0], s[3][1], s[3][2]);
    float mx = fmaxf(F3(F3(t0, t1, t2), t3, t4), s[3][3]);

    // lazy max: reduce + rescale only on breach (P bounded by 2^8)
    if (!__all(mx - mrow <= 8.0f)) {
      float Mx = fmaxf(mx, __shfl_xor(mx, 16, 64));
      Mx = fmaxf(Mx, __shfl_xor(Mx, 32, 64));
      float mnew = fmaxf(mrow, Mx);
      float al = exp2_hw(mrow - mnew);
      lrow *= al;
#pragma unroll
      for (int di = 0; di < 4; ++di)
#pragma unroll
        for (int i = 0; i < 4; ++i) o[di][i] *= al;
      mrow = mnew;
    }

    // exp (hardware, independent ops) + tree-sum (depth 4, reassociated)
    float p0  = exp2_hw(s[0][0] - mrow), p1  = exp2_hw(s[0][1] - mrow);
    float p2  = exp2_hw(s[0][2] - mrow), p3  = exp2_hw(s[0][3] - mrow);
    float p4  = exp2_hw(s[1][0] - mrow), p5  = exp2_hw(s[1][1] - mrow);
    float p6  = exp2_hw(s[1][2] - mrow), p7  = exp2_hw(s[1][3] - mrow);
    float p8  = exp2_hw(s[2][0] - mrow), p9  = exp2_hw(s[2][1] - mrow);
    float p10 = exp2_hw(s[2][2] - mrow), p11 = exp2_hw(s[2][3] - mrow);
    float p12 = exp2_hw(s[3][0] - mrow), p13 = exp2_hw(s[3][1] - mrow);
    float p14 = exp2_hw(s[3][2] - mrow), p15 = exp2_hw(s[3][3] - mrow);
    float a0 = p0 + p1, a1 = p2 + p3, a2 = p4 + p5, a3 = p6 + p7;
    float a4 = p8 + p9, a5 = p10 + p11, a6 = p12 + p13, a7 = p14 + p15;
    float b0 = a0 + a1, b1 = a2 + a3, b2 = a4 + a5, b3 = a6 + a7;
    lrow += (b0 + b1) + (b2 + b3);   // per-lane partial; reduced in epilogue

    // P[q][kv] wave-private, packed b64 writes, row-swizzled
    {
      uint2 pk;
      pk.x = cvt_pk_bf16(p0, p1);   pk.y = cvt_pk_bf16(p2, p3);
      *(uint2*)&Pw[l15 * 64 + ((0 * 16 + g * 4) ^ ((l15 & 7) << 3))] = pk;
      pk.x = cvt_pk_bf16(p4, p5);   pk.y = cvt_pk_bf16(p6, p7);
      *(uint2*)&Pw[l15 * 64 + ((1 * 16 + g * 4) ^ ((l15 & 7) << 3))] = pk;
      pk.x = cvt_pk_bf16(p8, p9);   pk.y = cvt_pk_bf16(p10, p11);
      *(uint2*)&Pw[l15 * 64 + ((2 * 16 + g * 4) ^ ((l15 & 7) << 3))] = pk;
      pk.x = cvt_pk_bf16(p12, p13); pk.y = cvt_pk_bf16(p14, p15);
      *(uint2*)&Pw[l15 * 64 + ((3 * 16 + g * 4) ^ ((l15 & 7) << 3))] = pk;
    }
    asm volatile("s_waitcnt lgkmcnt(0)" ::: "memory");
    __builtin_amdgcn_sched_barrier(0);

    // O^T += mfma(V, P): A = V^T rows (d), B = P rows (q = l15)
    __builtin_amdgcn_s_setprio(1);
#pragma unroll
    for (int kk = 0; kk < 2; ++kk) {
      bf8_t pf = *(const bf8_t*)&Pw[l15 * 64 + ((kk * 32 + g * 8) ^ ((l15 & 7) << 3))];
#pragma unroll
      for (int di = 0; di < 4; ++di) {
        int vrow = di * 16 + l15;
        bf8_t vf = *(const bf8_t*)&Vlc[(vrow * 64 + kk * 32 + g * 8) ^ swz(vrow)];
        o[di] = __builtin_amdgcn_mfma_f32_16x16x32_bf16(vf, pf, o[di], 0, 0, 0);
      }
    }
    __builtin_amdgcn_s_setprio(0);

    // all waves done reading buf[cur]; then refill it for tile t+2
    BAR2();
    if (t + 2 < 16) stage(t + 2, cur);
  }

  // epilogue: reduce per-lane partial denominator once
  lrow += __shfl_xor(lrow, 16, 64);
  lrow += __shfl_xor(lrow, 32, 64);
  float rinv = 1.0f / lrow;
#pragma unroll
  for (int di = 0; di < 4; ++di) {
    uint2 pk;
    pk.x = cvt_pk_bf16(o[di][0] * rinv, o[di][1] * rinv);
    pk.y = cvt_pk_bf16(o[di][2] * rinv, o[di][3] * rinv);
    int oe = l15 * 64 + ((di * 16 + g * 4) ^ ((l15 & 7) << 3));
    *(uint2*)&Pw[oe] = pk;
  }
  asm volatile("s_waitcnt lgkmcnt(0)" ::: "memory");
  __builtin_amdgcn_sched_barrier(0);

  const int bb = bh / H_, h = bh - bb * H_;
  const int rr = lane >> 2, cb = (lane & 3) * 16;
#pragma unroll
  for (int m2 = 0; m2 < 2; ++m2) {
    int e = rr * 64 + ((cb + 8 * m2) ^ ((rr & 7) << 3));
    bf8_t val = *(const bf8_t*)&Pw[e];
    unsigned short* dst =
        ctx + ((size_t)bb * N_ + qt * 64 + wv * 16 + rr) * E_ + h * HD_ + cb + 8 * m2;
    *(bf8_t*)dst = val;
  }
}

// ---------------- launch ----------------
extern "C" void kernel_launch(void* const* d_in, const int* in_sizes, int n_in,
                              void* d_out, int out_size, void* d_ws, size_t ws_size,
                              hipStream_t stream) {
  const float* x     = (const float*)d_in[0];
  const float* ln_g  = (const float*)d_in[1];
  const float* ln_b  = (const float*)d_in[2];
  const float* w_qkv = (const float*)d_in[3];
  const float* b_qkv = (const float*)d_in[4];
  const float* w_out = (const float*)d_in[5];
  const float* b_out = (const float*)d_in[6];
  float* out = (float*)d_out;

  char* ws = (char*)d_ws;
  const size_t SZ = (size_t)M_ * E_ * 2;  // 12.58 MB per bf16 activation
  unsigned short* xn    = (unsigned short*)(ws);
  unsigned short* qb    = (unsigned short*)(ws + SZ);
  unsigned short* kbuf  = (unsigned short*)(ws + 2 * SZ);
  unsigned short* vtb   = (unsigned short*)(ws + 3 * SZ);
  unsigned short* ctx   = (unsigned short*)(ws + 4 * SZ);
  unsigned short* wqkvb = (unsigned short*)(ws + 5 * SZ);
  unsigned short* woutb = (unsigned short*)(ws + 5 * SZ + (size_t)3 * E_ * E_ * 2);

  int n1 = 3 * E_ * E_ / 4;
  k_cast_bf16<<<(n1 + 255) / 256, 256, 0, stream>>>(w_qkv, wqkvb, n1);
  int n2 = E_ * E_ / 4;
  k_cast_bf16<<<(n2 + 255) / 256, 256, 0, stream>>>(w_out, woutb, n2);

  k_ln<<<M_, 192, 0, stream>>>(x, ln_g, ln_b, xn);

  k_gemm_bt<0><<<dim3(18, 64), 256, 0, stream>>>(xn, wqkvb, b_qkv, qb, kbuf, vtb,
                                                 nullptr, E_, 3 * E_);
  k_attn<<<dim3(96, 16), 256, 0, stream>>>(qb, kbuf, vtb, ctx);
  k_gemm_bt<1><<<dim3(6, 64), 256, 0, stream>>>(ctx, woutb, b_out, nullptr, nullptr,
                                                nullptr, out, E_, E_);
}